// Round 13
// baseline (378.792 us; speedup 1.0000x reference)
//
#include <hip/hip_runtime.h>

#define BB 128
#define NN 512
#define DD 128

// ---------------- kernel 1: h -> normalized hn ----------------
__global__ __launch_bounds__(256) void hn_kernel(const float* __restrict__ h,
                                                 const float* __restrict__ W0,
                                                 const float* __restrict__ W1,
                                                 float* __restrict__ hn) {
    int wave = (int)((blockIdx.x * blockDim.x + threadIdx.x) >> 6);  // 0..B*N-1
    int lane = threadIdx.x & 63;
    const float2* h2 = (const float2*)(h + (size_t)wave * DD);
    float2 w0 = ((const float2*)W0)[lane];
    float2 w1 = ((const float2*)W1)[lane];
    float2 x = h2[lane];
    float p0 = fmaxf(x.x * w0.x, 0.0f) * w1.x;
    float p1 = fmaxf(x.y * w0.y, 0.0f) * w1.y;
    float ss = p0 * p0 + p1 * p1;
#pragma unroll
    for (int m = 32; m; m >>= 1) ss += __shfl_xor(ss, m);
    float inv = 1.0f / (sqrtf(ss) + 1e-12f);
    float2 o;
    o.x = p0 * inv;
    o.y = p1 * inv;
    ((float2*)(hn + (size_t)wave * DD))[lane] = o;
}

// ------- kernel 2: K = exp(2*(hn hn^T + eye) - 2), SYMMETRIC tiles --------
// R28: T14 async-STAGE split. R27 triangulation: sim ~ 130-140us vs a ~40us
// VALU/LDS floor -> bound by EXPOSED staging latency (serial load->LDS->
// barrier->compute per KC chunk; 4 blocks/CU march in lockstep so stalls
// synchronize). Fix: hold chunk in regs, store to LDS post-barrier, issue
// NEXT chunk's loads BEFORE compute (~5.5K cyc compute hides ~300cyc
// L2-warm loads). kk-loop/fmaf k-order/expf/mirror untouched ->
// bitwise-identical K. Regs: acc 64 + staged 32 + misc ~116 <= 128.
#define KC 32
__global__ __launch_bounds__(256) void sim_kernel(const float* __restrict__ hn,
                                                  const int* __restrict__ lengths,
                                                  float* __restrict__ K) {
    __shared__ float As[KC][132];
    __shared__ float Bs[KC][132];
    __shared__ int pre[BB + 1];  // prefix sum of per-batch UPPER-TRI tile counts
    int tid = threadIdx.x;
    if (tid == 0) {
        int acc = 0;
        for (int b = 0; b < BB; b++) {
            pre[b] = acc;
            int len = max(lengths[b], 1);
            int nt = (len + 127) >> 7;
            acc += nt * (nt + 1) / 2;
        }
        pre[BB] = acc;
    }
    __syncthreads();
    int total = pre[BB];

    int lr = tid >> 3;
    int lk = (tid & 7) << 2;
    int tx = tid & 15, ty = tid >> 4;

    for (int t = blockIdx.x; t < total; t += gridDim.x) {
        int lo = 0, hi = BB;
        while (lo + 1 < hi) {
            int mid = (lo + hi) >> 1;
            if (pre[mid] <= t) lo = mid; else hi = mid;
        }
        int b = lo;
        int local = t - pre[b];
        int len = max(lengths[b], 1);
        int nt = (len + 127) >> 7;
        int ti = 0, rem = local;
        while (rem >= nt - ti) { rem -= nt - ti; ti++; }
        int tj = ti + rem;
        int r0 = ti << 7, c0 = tj << 7;
        const float* base = hn + (size_t)b * NN * DD;
        float acc[8][8] = {};

        // ---- T14 prologue: load chunk kc=0 into registers ----------------
        float4 sA0, sA1, sA2, sA3, sB0, sB1, sB2, sB3;
#define LOADC(kcc)                                                           \
        sA0 = *(const float4*)(base + (size_t)(r0 + lr +  0) * DD + (kcc) + lk); \
        sA1 = *(const float4*)(base + (size_t)(r0 + lr + 32) * DD + (kcc) + lk); \
        sA2 = *(const float4*)(base + (size_t)(r0 + lr + 64) * DD + (kcc) + lk); \
        sA3 = *(const float4*)(base + (size_t)(r0 + lr + 96) * DD + (kcc) + lk); \
        sB0 = *(const float4*)(base + (size_t)(c0 + lr +  0) * DD + (kcc) + lk); \
        sB1 = *(const float4*)(base + (size_t)(c0 + lr + 32) * DD + (kcc) + lk); \
        sB2 = *(const float4*)(base + (size_t)(c0 + lr + 64) * DD + (kcc) + lk); \
        sB3 = *(const float4*)(base + (size_t)(c0 + lr + 96) * DD + (kcc) + lk);
        LOADC(0)

        for (int kc = 0; kc < DD; kc += KC) {
            __syncthreads();  // previous chunk fully consumed (or first iter)
            // store staged registers -> LDS (transposed layout, unchanged)
#define STOREC(sAx, sBx, rr)                                                 \
            As[lk + 0][lr + rr] = sAx.x; As[lk + 1][lr + rr] = sAx.y;        \
            As[lk + 2][lr + rr] = sAx.z; As[lk + 3][lr + rr] = sAx.w;        \
            Bs[lk + 0][lr + rr] = sBx.x; Bs[lk + 1][lr + rr] = sBx.y;        \
            Bs[lk + 2][lr + rr] = sBx.z; Bs[lk + 3][lr + rr] = sBx.w;
            STOREC(sA0, sB0, 0)
            STOREC(sA1, sB1, 32)
            STOREC(sA2, sB2, 64)
            STOREC(sA3, sB3, 96)
#undef STOREC
            // issue NEXT chunk's loads now -- they fly during compute
            if (kc + KC < DD) { LOADC(kc + KC) }
            __syncthreads();
#pragma unroll
            for (int kk = 0; kk < KC; kk++) {
                float4 a0 = *(const float4*)&As[kk][ty * 8];
                float4 a1 = *(const float4*)&As[kk][ty * 8 + 4];
                float4 b0 = *(const float4*)&Bs[kk][tx * 4];
                float4 b1 = *(const float4*)&Bs[kk][64 + tx * 4];
                float ar[8] = {a0.x, a0.y, a0.z, a0.w, a1.x, a1.y, a1.z, a1.w};
                float bc[8] = {b0.x, b0.y, b0.z, b0.w, b1.x, b1.y, b1.z, b1.w};
#pragma unroll
                for (int r = 0; r < 8; r++)
#pragma unroll
                    for (int c = 0; c < 8; c++)
                        acc[r][c] = fmaf(ar[r], bc[c], acc[r][c]);
            }
        }
#undef LOADC
        float* out = K + (size_t)b * NN * NN;
        // ---- direct tile (ti,tj) -----------------------------------------
#pragma unroll
        for (int r = 0; r < 8; r++) {
            int i = r0 + ty * 8 + r;
            if (i >= len) continue;
#pragma unroll
            for (int cg = 0; cg < 2; cg++) {
                int j0 = c0 + cg * 64 + tx * 4;
                if (j0 >= len) continue;
                float vv[4];
#pragma unroll
                for (int c = 0; c < 4; c++) {
                    float s = acc[r][cg * 4 + c] + ((i == j0 + c) ? 1.0f : 0.0f);
                    vv[c] = expf(2.0f * s - 2.0f);
                }
                float4 o;
                o.x = vv[0]; o.y = vv[1]; o.z = vv[2]; o.w = vv[3];
                *(float4*)(out + (size_t)i * NN + j0) = o;
            }
        }
        // ---- mirror tile (tj,ti) via LDS transpose -----------------------
        if (ti != tj) {
#pragma unroll
            for (int cg = 0; cg < 2; cg++) {
                for (int half = 0; half < 2; half++) {
                    __syncthreads();
                    if ((tx >> 3) == half) {
                        int jl = (tx & 7) * 4;
#pragma unroll
                        for (int r = 0; r < 8; r++)
#pragma unroll
                            for (int c = 0; c < 4; c++)
                                As[jl + c][ty * 8 + r] = acc[r][cg * 4 + c];
                    }
                    __syncthreads();
                    int jrow = tid >> 3;
                    int j = c0 + cg * 64 + half * 32 + jrow;
                    if (j < len) {
                        int ib = (tid & 7) * 16;
#pragma unroll
                        for (int s4 = 0; s4 < 4; s4++) {
                            int il = ib + s4 * 4;
                            int i0 = r0 + il;
                            if (i0 >= len) continue;
                            float4 sraw = *(const float4*)&As[jrow][il];
                            float4 o;
                            o.x = expf(2.0f * sraw.x - 2.0f);
                            o.y = expf(2.0f * sraw.y - 2.0f);
                            o.z = expf(2.0f * sraw.z - 2.0f);
                            o.w = expf(2.0f * sraw.w - 2.0f);
                            *(float4*)(out + (size_t)j * NN + i0) = o;
                        }
                    }
                }
            }
            __syncthreads();
        }
    }
}

__device__ __forceinline__ float dot8(float4 A, float4 B, float4 x0, float4 x1) {
    float d = fmaf(A.x, x0.x, fmaf(A.y, x0.y, fmaf(A.z, x0.z, A.w * x0.w)));
    return fmaf(B.x, x1.x, fmaf(B.y, x1.y, fmaf(B.z, x1.z, fmaf(B.w, x1.w, d))));
}

// ---------------- persistent Sinkhorn: 20 iters, K register-resident ------
// R27 config (proven: coop 134 warm, absmax 0.0). HARD CONSTRAINT (R26):
// 512-thread block needs 2 waves/SIMD -> ~256 regs/thread cap; 176-row
// cache is the proven maximum (256 rows spilled to scratch, 3x regression).
// Protocol (R24): (tag<<32|float_bits(s0)) u64 agent atomic per column;
// consumer polls its own column of each sibling. Single RT; 2-parity.
#define ROWS22(X) X(0) X(1) X(2) X(3) X(4) X(5) X(6) X(7) X(8) X(9) X(10) \
    X(11) X(12) X(13) X(14) X(15) X(16) X(17) X(18) X(19) X(20) X(21)

__global__ __launch_bounds__(512, 2) void coop_sink(const float* __restrict__ K,
                                                    float* __restrict__ u_buf,
                                                    float* __restrict__ v_buf,
                                                    const int* __restrict__ lengths,
                                                    unsigned long long* __restrict__ slots64) {
    __shared__ float xb[NN];      // current multiplier vector (v)
    __shared__ float pv[8 * NN];  // per-wave column partials (16 KB)
    __shared__ int Sh[BB], Pre[BB];

    int g = blockIdx.x;
    int tid = threadIdx.x;

    // ---- deterministic GLOBAL schedule: S_b = ceil(len/176), sum <= 256 ---
    if (tid == 0) {
        int need[BB]; int ssum = 0;
        for (int m = 0; m < BB; m++) {
            int L = max(lengths[m], 1);
            need[m] = (L + 175) / 176;  // 1..3
            ssum += need[m];
        }
        while (ssum > 256) {  // rare: shrink the largest (first on tie)
            int best = 0, bv = need[0];
            for (int m = 1; m < BB; m++)
                if (need[m] > bv) { bv = need[m]; best = m; }
            need[best]--; ssum--;
        }
        int acc = 0;
        for (int m = 0; m < BB; m++) { Pre[m] = acc; Sh[m] = need[m]; acc += need[m]; }
    }
    __syncthreads();

    int m = -1;
    for (int mm = 0; mm < BB; mm++)
        if (g >= Pre[mm] && g < Pre[mm] + Sh[mm]) { m = mm; break; }
    if (m < 0) return;  // surplus block: idle
    int b = m;                  // batch
    int jbase = Pre[m];
    int q = g - jbase;          // slice within batch
    int S = Sh[m];              // slices for this batch (<=3)

    int len = max(lengths[b], 1);
    int len4 = (len + 3) & ~3;
    int rpq = (len + S - 1) / S;
    int r_lo = q * rpq;
    int nrows = min(len - r_lo, rpq);
    if (nrows < 0) nrows = 0;
    float inv_n = 1.0f / (float)len;

    int w = tid >> 6, l = tid & 63;
    int c0 = 4 * l, c1 = 256 + 4 * l;
    bool a0 = c0 < len4, a1 = c1 < len4;
    const float* Kb = K + (size_t)b * NN * NN;

    xb[tid] = (tid < len) ? 1.0f : 0.0f;

    // ---- register-resident K slice: rows w+8o (o<22), named scalars -------
#define DECL(o) float4 kA##o = {0,0,0,0}, kB##o = {0,0,0,0};
    ROWS22(DECL)
#undef DECL
#define FILL_ROW(o)                                                          \
    {                                                                        \
        int i_ = w + 8 * (o);                                                \
        if (i_ < nrows) {                                                    \
            const float* g0_ = Kb + (size_t)(r_lo + i_) * NN;                \
            if (a0) kA##o = *(const float4*)(g0_ + c0);                      \
            if (a1) kB##o = *(const float4*)(g0_ + c1);                      \
        }                                                                    \
    }
    ROWS22(FILL_ROW)
#undef FILL_ROW

    __syncthreads();

    for (int t = 0; t < 20; t++) {
        float4 xv0 = *(const float4*)(xb + c0);
        float4 xv1 = *(const float4*)(xb + c1);
        float4 pa = {0, 0, 0, 0}, pb = {0, 0, 0, 0};

        // ---- phase A (cached): 22 rows/wave entirely from registers ----
#define DOT(o) float d##o = dot8(kA##o, kB##o, xv0, xv1);
        ROWS22(DOT)
#undef DOT
#pragma unroll
        for (int mm2 = 32; mm2; mm2 >>= 1) {  // 22 interleaved butterfly chains
#define BF(o) d##o += __shfl_xor(d##o, mm2);
            ROWS22(BF)
#undef BF
        }
#define RC(o) float uu##o = inv_n / (d##o + 1e-9f);
        ROWS22(RC)
#undef RC
#define ACC_ROW(o)                                                           \
    pa.x = fmaf(kA##o.x, uu##o, pa.x); pa.y = fmaf(kA##o.y, uu##o, pa.y);    \
    pa.z = fmaf(kA##o.z, uu##o, pa.z); pa.w = fmaf(kA##o.w, uu##o, pa.w);    \
    pb.x = fmaf(kB##o.x, uu##o, pb.x); pb.y = fmaf(kB##o.y, uu##o, pb.y);    \
    pb.z = fmaf(kB##o.z, uu##o, pb.z); pb.w = fmaf(kB##o.w, uu##o, pb.w);
        ROWS22(ACC_ROW)
#undef ACC_ROW
        if (t == 19 && l == 0) {
            float* ub = u_buf + (size_t)b * NN + r_lo + w;
#define ST(o) if (w + 8 * (o) < nrows) ub[8 * (o)] = uu##o;
            ROWS22(ST)
#undef ST
        }

        // ---- phase A (streamed): rows >= 176, only in rare overflow cases -
        for (int i = 176 + w; i < nrows; i += 8) {
            const float* g0 = Kb + (size_t)(r_lo + i) * NN;
            float4 A = {0, 0, 0, 0}, B = {0, 0, 0, 0};
            if (a0) A = *(const float4*)(g0 + c0);
            if (a1) B = *(const float4*)(g0 + c1);
            float d = dot8(A, B, xv0, xv1);
#pragma unroll
            for (int mm2 = 32; mm2; mm2 >>= 1) d += __shfl_xor(d, mm2);
            float uu = inv_n / (d + 1e-9f);
            pa.x = fmaf(A.x, uu, pa.x); pa.y = fmaf(A.y, uu, pa.y);
            pa.z = fmaf(A.z, uu, pa.z); pa.w = fmaf(A.w, uu, pa.w);
            pb.x = fmaf(B.x, uu, pb.x); pb.y = fmaf(B.y, uu, pb.y);
            pb.z = fmaf(B.z, uu, pb.z); pb.w = fmaf(B.w, uu, pb.w);
            if (t == 19 && l == 0) u_buf[(size_t)b * NN + r_lo + i] = uu;
        }

        // ---- phase B: LDS reduce, publish (tag|value) u64 per column ------
        *(float4*)(pv + w * NN + c0) = pa;
        *(float4*)(pv + w * NN + c1) = pb;
        __syncthreads();
        int c = tid;  // one column per thread
        float s0 = pv[c] + pv[NN + c] + pv[2 * NN + c] + pv[3 * NN + c] +
                   pv[4 * NN + c] + pv[5 * NN + c] + pv[6 * NN + c] + pv[7 * NN + c];
        unsigned long long* pbase =
            slots64 + ((size_t)(t & 1) * 512) * 512;  // parity region
        if (S > 1) {
            unsigned long long pk =
                ((unsigned long long)(unsigned)(t + 1) << 32) | __float_as_uint(s0);
            __hip_atomic_store(pbase + (size_t)g * 512 + c, pk,
                               __ATOMIC_RELAXED, __HIP_MEMORY_SCOPE_AGENT);
        }

        // ---- phase C: poll sibling columns (1 RT), v = mu/(colsum+eps) ----
        float t0 = s0;
        for (int s = 1; s < S; s++) {
            int k = q + s; if (k >= S) k -= S;  // stagger sibling order
            const unsigned long long* p64 = pbase + (size_t)(jbase + k) * 512 + c;
            unsigned long long vpk =
                __hip_atomic_load(p64, __ATOMIC_RELAXED, __HIP_MEMORY_SCOPE_AGENT);
            while ((unsigned)(vpk >> 32) != (unsigned)(t + 1)) {
                __builtin_amdgcn_s_sleep(1);
                vpk = __hip_atomic_load(p64, __ATOMIC_RELAXED, __HIP_MEMORY_SCOPE_AGENT);
            }
            t0 += __uint_as_float((unsigned)vpk);
        }
        float v0 = (c < len) ? (inv_n / (t0 + 1e-9f)) : 0.0f;
        if (t < 19) {
            xb[c] = v0;
        } else if (c >= r_lo && c < r_lo + nrows) {
            v_buf[(size_t)b * NN + c] = v0;  // owner writes final v
        }
        __syncthreads();  // xb ready + pv consumed before next iteration
    }
}

// ---------------- kernel 4: fused epilogue, in-place on d_out -------------
__global__ __launch_bounds__(256) void epi_kernel(float* __restrict__ io,
                                                  const float* __restrict__ u,
                                                  const float* __restrict__ v,
                                                  const int* __restrict__ lengths) {
    const float E5 = 0.006737946999085467f;  // exp(-5)
    size_t idx = (size_t)blockIdx.x * 256 + threadIdx.x;  // float4 index
    int b = (int)(idx >> 16);
    int r = (int)(idx >> 7) & (NN - 1);
    int c4 = ((int)idx & 127) << 2;
    int len = max(lengths[b], 1);
    float4 o;
    if (r >= len || c4 >= len) {
        o.x = E5; o.y = E5; o.z = E5; o.w = E5;
        ((float4*)io)[idx] = o;
        return;
    }
    float4 k = ((float4*)io)[idx];
    float ui = u[(size_t)b * NN + r];
    float4 vv = *(const float4*)(v + (size_t)b * NN + c4);
    float t = (float)len * ui;
    float kv[4] = {k.x, k.y, k.z, k.w};
    float vj[4] = {vv.x, vv.y, vv.z, vv.w};
    float ov[4];
#pragma unroll
    for (int c = 0; c < 4; c++) {
        float Kc = kv[c];
        float P = t * Kc * vj[c];
        bool valid = (c4 + c) < len;
        if (valid && P > 0.1f) {
            float x = 2.5f * logf(Kc);  // == 5*sim - 5
            ov[c] = (x > 0.0f) ? (x + 1.0f) : expf(x);
        } else {
            ov[c] = E5;
        }
    }
    o.x = ov[0]; o.y = ov[1]; o.z = ov[2]; o.w = ov[3];
    ((float4*)io)[idx] = o;
}

extern "C" void kernel_launch(void* const* d_in, const int* in_sizes, int n_in,
                              void* d_out, int out_size, void* d_ws, size_t ws_size,
                              hipStream_t stream) {
    const float* h = (const float*)d_in[0];
    const float* W0 = (const float*)d_in[1];
    const float* W1 = (const float*)d_in[2];
    const int* lengths = (const int*)d_in[3];
    float* K = (float*)d_out;  // [B,N,N] K, overwritten in place by epilogue

    char* ws = (char*)d_ws;
    float* hn = (float*)ws;                                   // 33.5 MB
    size_t off = (size_t)BB * NN * DD * 4;
    float* u = (float*)(ws + off); off += (size_t)BB * NN * 4;                    // 256 KB
    float* v = (float*)(ws + off); off += (size_t)BB * NN * 4;                    // 256 KB
    unsigned long long* slots64 = (unsigned long long*)(ws + off);
    off += (size_t)2 * 512 * 512 * 8;                                             // 4.2 MB

    hn_kernel<<<BB * NN / 4, 256, 0, stream>>>(h, W0, W1, hn);
    sim_kernel<<<1024, 256, 0, stream>>>(hn, lengths, K);

    // 256 blocks x 512 thr, 1 block/CU; 176 rows cached/block (HARD CAP,
    // see R26 note), S<=3; single-RT (tag|value) u64 exchange (R24).
    coop_sink<<<256, 512, 0, stream>>>(K, u, v, lengths, slots64);

    epi_kernel<<<(unsigned)((size_t)BB * NN * NN / 4 / 256), 256, 0, stream>>>(K, u, v, lengths);
}

// Round 14
// 358.520 us; speedup vs baseline: 1.0565x; 1.0565x over previous
//
#include <hip/hip_runtime.h>

#define BB 128
#define NN 512
#define DD 128

// ---------------- kernel 1: h -> normalized hn ----------------
__global__ __launch_bounds__(256) void hn_kernel(const float* __restrict__ h,
                                                 const float* __restrict__ W0,
                                                 const float* __restrict__ W1,
                                                 float* __restrict__ hn) {
    int wave = (int)((blockIdx.x * blockDim.x + threadIdx.x) >> 6);  // 0..B*N-1
    int lane = threadIdx.x & 63;
    const float2* h2 = (const float2*)(h + (size_t)wave * DD);
    float2 w0 = ((const float2*)W0)[lane];
    float2 w1 = ((const float2*)W1)[lane];
    float2 x = h2[lane];
    float p0 = fmaxf(x.x * w0.x, 0.0f) * w1.x;
    float p1 = fmaxf(x.y * w0.y, 0.0f) * w1.y;
    float ss = p0 * p0 + p1 * p1;
#pragma unroll
    for (int m = 32; m; m >>= 1) ss += __shfl_xor(ss, m);
    float inv = 1.0f / (sqrtf(ss) + 1e-12f);
    float2 o;
    o.x = p0 * inv;
    o.y = p1 * inv;
    ((float2*)(hn + (size_t)wave * DD))[lane] = o;
}

// ------- kernel 2: K = exp(2*(hn hn^T + eye) - 2), SYMMETRIC tiles --------
// R25 (final): only ti<=tj tiles computed; mirror tile written via LDS
// transpose of RAW acc + identical expf(2s-2) -> bitwise-identical K.
// R28 POST-MORTEM: T14 async-stage split REGRESSED sim +20us (staged regs
// cost an occupancy step; inter-block drift already hid staging latency).
// Do not re-apply. This simple form is sim's proven best.
#define KC 32
__global__ __launch_bounds__(256) void sim_kernel(const float* __restrict__ hn,
                                                  const int* __restrict__ lengths,
                                                  float* __restrict__ K) {
    __shared__ float As[KC][132];
    __shared__ float Bs[KC][132];
    __shared__ int pre[BB + 1];  // prefix sum of per-batch UPPER-TRI tile counts
    int tid = threadIdx.x;
    if (tid == 0) {
        int acc = 0;
        for (int b = 0; b < BB; b++) {
            pre[b] = acc;
            int len = max(lengths[b], 1);
            int nt = (len + 127) >> 7;
            acc += nt * (nt + 1) / 2;
        }
        pre[BB] = acc;
    }
    __syncthreads();
    int total = pre[BB];

    int lr = tid >> 3;
    int lk = (tid & 7) << 2;
    int tx = tid & 15, ty = tid >> 4;

    for (int t = blockIdx.x; t < total; t += gridDim.x) {
        int lo = 0, hi = BB;
        while (lo + 1 < hi) {
            int mid = (lo + hi) >> 1;
            if (pre[mid] <= t) lo = mid; else hi = mid;
        }
        int b = lo;
        int local = t - pre[b];
        int len = max(lengths[b], 1);
        int nt = (len + 127) >> 7;
        int ti = 0, rem = local;
        while (rem >= nt - ti) { rem -= nt - ti; ti++; }
        int tj = ti + rem;
        int r0 = ti << 7, c0 = tj << 7;
        const float* base = hn + (size_t)b * NN * DD;
        float acc[8][8] = {};

        for (int kc = 0; kc < DD; kc += KC) {
#pragma unroll
            for (int rr = 0; rr < 128; rr += 32) {
                float4 a = *(const float4*)(base + (size_t)(r0 + lr + rr) * DD + kc + lk);
                As[lk + 0][lr + rr] = a.x; As[lk + 1][lr + rr] = a.y;
                As[lk + 2][lr + rr] = a.z; As[lk + 3][lr + rr] = a.w;
                float4 bb = *(const float4*)(base + (size_t)(c0 + lr + rr) * DD + kc + lk);
                Bs[lk + 0][lr + rr] = bb.x; Bs[lk + 1][lr + rr] = bb.y;
                Bs[lk + 2][lr + rr] = bb.z; Bs[lk + 3][lr + rr] = bb.w;
            }
            __syncthreads();
#pragma unroll
            for (int kk = 0; kk < KC; kk++) {
                float4 a0 = *(const float4*)&As[kk][ty * 8];
                float4 a1 = *(const float4*)&As[kk][ty * 8 + 4];
                float4 b0 = *(const float4*)&Bs[kk][tx * 4];
                float4 b1 = *(const float4*)&Bs[kk][64 + tx * 4];
                float ar[8] = {a0.x, a0.y, a0.z, a0.w, a1.x, a1.y, a1.z, a1.w};
                float bc[8] = {b0.x, b0.y, b0.z, b0.w, b1.x, b1.y, b1.z, b1.w};
#pragma unroll
                for (int r = 0; r < 8; r++)
#pragma unroll
                    for (int c = 0; c < 8; c++)
                        acc[r][c] = fmaf(ar[r], bc[c], acc[r][c]);
            }
            __syncthreads();
        }
        float* out = K + (size_t)b * NN * NN;
        // ---- direct tile (ti,tj) -----------------------------------------
#pragma unroll
        for (int r = 0; r < 8; r++) {
            int i = r0 + ty * 8 + r;
            if (i >= len) continue;
#pragma unroll
            for (int cg = 0; cg < 2; cg++) {
                int j0 = c0 + cg * 64 + tx * 4;
                if (j0 >= len) continue;
                float vv[4];
#pragma unroll
                for (int c = 0; c < 4; c++) {
                    float s = acc[r][cg * 4 + c] + ((i == j0 + c) ? 1.0f : 0.0f);
                    vv[c] = expf(2.0f * s - 2.0f);
                }
                float4 o;
                o.x = vv[0]; o.y = vv[1]; o.z = vv[2]; o.w = vv[3];
                *(float4*)(out + (size_t)i * NN + j0) = o;
            }
        }
        // ---- mirror tile (tj,ti) via LDS transpose -----------------------
        if (ti != tj) {
#pragma unroll
            for (int cg = 0; cg < 2; cg++) {
                for (int half = 0; half < 2; half++) {
                    __syncthreads();
                    if ((tx >> 3) == half) {
                        int jl = (tx & 7) * 4;
#pragma unroll
                        for (int r = 0; r < 8; r++)
#pragma unroll
                            for (int c = 0; c < 4; c++)
                                As[jl + c][ty * 8 + r] = acc[r][cg * 4 + c];
                    }
                    __syncthreads();
                    int jrow = tid >> 3;
                    int j = c0 + cg * 64 + half * 32 + jrow;
                    if (j < len) {
                        int ib = (tid & 7) * 16;
#pragma unroll
                        for (int s4 = 0; s4 < 4; s4++) {
                            int il = ib + s4 * 4;
                            int i0 = r0 + il;
                            if (i0 >= len) continue;
                            float4 sraw = *(const float4*)&As[jrow][il];
                            float4 o;
                            o.x = expf(2.0f * sraw.x - 2.0f);
                            o.y = expf(2.0f * sraw.y - 2.0f);
                            o.z = expf(2.0f * sraw.z - 2.0f);
                            o.w = expf(2.0f * sraw.w - 2.0f);
                            *(float4*)(out + (size_t)j * NN + i0) = o;
                        }
                    }
                }
            }
            __syncthreads();
        }
    }
}

__device__ __forceinline__ float dot8(float4 A, float4 B, float4 x0, float4 x1) {
    float d = fmaf(A.x, x0.x, fmaf(A.y, x0.y, fmaf(A.z, x0.z, A.w * x0.w)));
    return fmaf(B.x, x1.x, fmaf(B.y, x1.y, fmaf(B.z, x1.z, fmaf(B.w, x1.w, d))));
}

// ---------------- persistent Sinkhorn: 20 iters, K register-resident ------
// FINAL CONFIG (proven: total ~359us, coop 134 warm, absmax 0.0).
// HARD CONSTRAINTS, do not re-break:
//  - 512-thread block = 8 waves needs 2 waves/SIMD -> ~256 regs/thread cap
//    (m69). 176-row cache (+~60 working) is the proven max; 256 rows
//    spilled to scratch (R26: 3x regression).
//  - Agent-scope exchange bypasses per-XCD L2; protocol is already
//    single-RT (R24): (tag<<32|float_bits(s0)) u64 atomic per column,
//    consumer polls its own column of each sibling, value from same load.
//    2-parity regions; ~6.1us/iter is the measured visibility+skew floor.
//  - Fusing sim (R22) or epi (R23) into this kernel regresses (AGPR
//    accumulate 3x; latency-starved store tail).
#define ROWS22(X) X(0) X(1) X(2) X(3) X(4) X(5) X(6) X(7) X(8) X(9) X(10) \
    X(11) X(12) X(13) X(14) X(15) X(16) X(17) X(18) X(19) X(20) X(21)

__global__ __launch_bounds__(512, 2) void coop_sink(const float* __restrict__ K,
                                                    float* __restrict__ u_buf,
                                                    float* __restrict__ v_buf,
                                                    const int* __restrict__ lengths,
                                                    unsigned long long* __restrict__ slots64) {
    __shared__ float xb[NN];      // current multiplier vector (v)
    __shared__ float pv[8 * NN];  // per-wave column partials (16 KB)
    __shared__ int Sh[BB], Pre[BB];

    int g = blockIdx.x;
    int tid = threadIdx.x;

    // ---- deterministic GLOBAL schedule: S_b = ceil(len/176), sum <= 256 ---
    if (tid == 0) {
        int need[BB]; int ssum = 0;
        for (int m = 0; m < BB; m++) {
            int L = max(lengths[m], 1);
            need[m] = (L + 175) / 176;  // 1..3
            ssum += need[m];
        }
        while (ssum > 256) {  // rare: shrink the largest (first on tie)
            int best = 0, bv = need[0];
            for (int m = 1; m < BB; m++)
                if (need[m] > bv) { bv = need[m]; best = m; }
            need[best]--; ssum--;
        }
        int acc = 0;
        for (int m = 0; m < BB; m++) { Pre[m] = acc; Sh[m] = need[m]; acc += need[m]; }
    }
    __syncthreads();

    int m = -1;
    for (int mm = 0; mm < BB; mm++)
        if (g >= Pre[mm] && g < Pre[mm] + Sh[mm]) { m = mm; break; }
    if (m < 0) return;  // surplus block: idle
    int b = m;                  // batch
    int jbase = Pre[m];
    int q = g - jbase;          // slice within batch
    int S = Sh[m];              // slices for this batch (<=3)

    int len = max(lengths[b], 1);
    int len4 = (len + 3) & ~3;
    int rpq = (len + S - 1) / S;
    int r_lo = q * rpq;
    int nrows = min(len - r_lo, rpq);
    if (nrows < 0) nrows = 0;
    float inv_n = 1.0f / (float)len;

    int w = tid >> 6, l = tid & 63;
    int c0 = 4 * l, c1 = 256 + 4 * l;
    bool a0 = c0 < len4, a1 = c1 < len4;
    const float* Kb = K + (size_t)b * NN * NN;

    xb[tid] = (tid < len) ? 1.0f : 0.0f;

    // ---- register-resident K slice: rows w+8o (o<22), named scalars -------
#define DECL(o) float4 kA##o = {0,0,0,0}, kB##o = {0,0,0,0};
    ROWS22(DECL)
#undef DECL
#define FILL_ROW(o)                                                          \
    {                                                                        \
        int i_ = w + 8 * (o);                                                \
        if (i_ < nrows) {                                                    \
            const float* g0_ = Kb + (size_t)(r_lo + i_) * NN;                \
            if (a0) kA##o = *(const float4*)(g0_ + c0);                      \
            if (a1) kB##o = *(const float4*)(g0_ + c1);                      \
        }                                                                    \
    }
    ROWS22(FILL_ROW)
#undef FILL_ROW

    __syncthreads();

    for (int t = 0; t < 20; t++) {
        float4 xv0 = *(const float4*)(xb + c0);
        float4 xv1 = *(const float4*)(xb + c1);
        float4 pa = {0, 0, 0, 0}, pb = {0, 0, 0, 0};

        // ---- phase A (cached): 22 rows/wave entirely from registers ----
#define DOT(o) float d##o = dot8(kA##o, kB##o, xv0, xv1);
        ROWS22(DOT)
#undef DOT
#pragma unroll
        for (int mm2 = 32; mm2; mm2 >>= 1) {  // 22 interleaved butterfly chains
#define BF(o) d##o += __shfl_xor(d##o, mm2);
            ROWS22(BF)
#undef BF
        }
#define RC(o) float uu##o = inv_n / (d##o + 1e-9f);
        ROWS22(RC)
#undef RC
#define ACC_ROW(o)                                                           \
    pa.x = fmaf(kA##o.x, uu##o, pa.x); pa.y = fmaf(kA##o.y, uu##o, pa.y);    \
    pa.z = fmaf(kA##o.z, uu##o, pa.z); pa.w = fmaf(kA##o.w, uu##o, pa.w);    \
    pb.x = fmaf(kB##o.x, uu##o, pb.x); pb.y = fmaf(kB##o.y, uu##o, pb.y);    \
    pb.z = fmaf(kB##o.z, uu##o, pb.z); pb.w = fmaf(kB##o.w, uu##o, pb.w);
        ROWS22(ACC_ROW)
#undef ACC_ROW
        if (t == 19 && l == 0) {
            float* ub = u_buf + (size_t)b * NN + r_lo + w;
#define ST(o) if (w + 8 * (o) < nrows) ub[8 * (o)] = uu##o;
            ROWS22(ST)
#undef ST
        }

        // ---- phase A (streamed): rows >= 176, only in rare overflow cases -
        for (int i = 176 + w; i < nrows; i += 8) {
            const float* g0 = Kb + (size_t)(r_lo + i) * NN;
            float4 A = {0, 0, 0, 0}, B = {0, 0, 0, 0};
            if (a0) A = *(const float4*)(g0 + c0);
            if (a1) B = *(const float4*)(g0 + c1);
            float d = dot8(A, B, xv0, xv1);
#pragma unroll
            for (int mm2 = 32; mm2; mm2 >>= 1) d += __shfl_xor(d, mm2);
            float uu = inv_n / (d + 1e-9f);
            pa.x = fmaf(A.x, uu, pa.x); pa.y = fmaf(A.y, uu, pa.y);
            pa.z = fmaf(A.z, uu, pa.z); pa.w = fmaf(A.w, uu, pa.w);
            pb.x = fmaf(B.x, uu, pb.x); pb.y = fmaf(B.y, uu, pb.y);
            pb.z = fmaf(B.z, uu, pb.z); pb.w = fmaf(B.w, uu, pb.w);
            if (t == 19 && l == 0) u_buf[(size_t)b * NN + r_lo + i] = uu;
        }

        // ---- phase B: LDS reduce, publish (tag|value) u64 per column ------
        *(float4*)(pv + w * NN + c0) = pa;
        *(float4*)(pv + w * NN + c1) = pb;
        __syncthreads();
        int c = tid;  // one column per thread
        float s0 = pv[c] + pv[NN + c] + pv[2 * NN + c] + pv[3 * NN + c] +
                   pv[4 * NN + c] + pv[5 * NN + c] + pv[6 * NN + c] + pv[7 * NN + c];
        unsigned long long* pbase =
            slots64 + ((size_t)(t & 1) * 512) * 512;  // parity region
        if (S > 1) {
            unsigned long long pk =
                ((unsigned long long)(unsigned)(t + 1) << 32) | __float_as_uint(s0);
            __hip_atomic_store(pbase + (size_t)g * 512 + c, pk,
                               __ATOMIC_RELAXED, __HIP_MEMORY_SCOPE_AGENT);
        }

        // ---- phase C: poll sibling columns (1 RT), v = mu/(colsum+eps) ----
        float t0 = s0;
        for (int s = 1; s < S; s++) {
            int k = q + s; if (k >= S) k -= S;  // stagger sibling order
            const unsigned long long* p64 = pbase + (size_t)(jbase + k) * 512 + c;
            unsigned long long vpk =
                __hip_atomic_load(p64, __ATOMIC_RELAXED, __HIP_MEMORY_SCOPE_AGENT);
            while ((unsigned)(vpk >> 32) != (unsigned)(t + 1)) {
                __builtin_amdgcn_s_sleep(1);
                vpk = __hip_atomic_load(p64, __ATOMIC_RELAXED, __HIP_MEMORY_SCOPE_AGENT);
            }
            t0 += __uint_as_float((unsigned)vpk);
        }
        float v0 = (c < len) ? (inv_n / (t0 + 1e-9f)) : 0.0f;
        if (t < 19) {
            xb[c] = v0;
        } else if (c >= r_lo && c < r_lo + nrows) {
            v_buf[(size_t)b * NN + c] = v0;  // owner writes final v
        }
        __syncthreads();  // xb ready + pv consumed before next iteration
    }
}

// ---------------- kernel 4: fused epilogue, in-place on d_out -------------
__global__ __launch_bounds__(256) void epi_kernel(float* __restrict__ io,
                                                  const float* __restrict__ u,
                                                  const float* __restrict__ v,
                                                  const int* __restrict__ lengths) {
    const float E5 = 0.006737946999085467f;  // exp(-5)
    size_t idx = (size_t)blockIdx.x * 256 + threadIdx.x;  // float4 index
    int b = (int)(idx >> 16);
    int r = (int)(idx >> 7) & (NN - 1);
    int c4 = ((int)idx & 127) << 2;
    int len = max(lengths[b], 1);
    float4 o;
    if (r >= len || c4 >= len) {
        o.x = E5; o.y = E5; o.z = E5; o.w = E5;
        ((float4*)io)[idx] = o;
        return;
    }
    float4 k = ((float4*)io)[idx];
    float ui = u[(size_t)b * NN + r];
    float4 vv = *(const float4*)(v + (size_t)b * NN + c4);
    float t = (float)len * ui;
    float kv[4] = {k.x, k.y, k.z, k.w};
    float vj[4] = {vv.x, vv.y, vv.z, vv.w};
    float ov[4];
#pragma unroll
    for (int c = 0; c < 4; c++) {
        float Kc = kv[c];
        float P = t * Kc * vj[c];
        bool valid = (c4 + c) < len;
        if (valid && P > 0.1f) {
            float x = 2.5f * logf(Kc);  // == 5*sim - 5
            ov[c] = (x > 0.0f) ? (x + 1.0f) : expf(x);
        } else {
            ov[c] = E5;
        }
    }
    o.x = ov[0]; o.y = ov[1]; o.z = ov[2]; o.w = ov[3];
    ((float4*)io)[idx] = o;
}

extern "C" void kernel_launch(void* const* d_in, const int* in_sizes, int n_in,
                              void* d_out, int out_size, void* d_ws, size_t ws_size,
                              hipStream_t stream) {
    const float* h = (const float*)d_in[0];
    const float* W0 = (const float*)d_in[1];
    const float* W1 = (const float*)d_in[2];
    const int* lengths = (const int*)d_in[3];
    float* K = (float*)d_out;  // [B,N,N] K, overwritten in place by epilogue

    char* ws = (char*)d_ws;
    float* hn = (float*)ws;                                   // 33.5 MB
    size_t off = (size_t)BB * NN * DD * 4;
    float* u = (float*)(ws + off); off += (size_t)BB * NN * 4;                    // 256 KB
    float* v = (float*)(ws + off); off += (size_t)BB * NN * 4;                    // 256 KB
    unsigned long long* slots64 = (unsigned long long*)(ws + off);
    off += (size_t)2 * 512 * 512 * 8;                                             // 4.2 MB

    hn_kernel<<<BB * NN / 4, 256, 0, stream>>>(h, W0, W1, hn);
    sim_kernel<<<1024, 256, 0, stream>>>(hn, lengths, K);

    // 256 blocks x 512 thr, 1 block/CU; 176 rows cached/block (HARD CAP,
    // see coop note), S<=3; single-RT (tag|value) u64 exchange (R24).
    coop_sink<<<256, 512, 0, stream>>>(K, u, v, lengths, slots64);

    epi_kernel<<<(unsigned)((size_t)BB * NN * NN / 4 / 256), 256, 0, stream>>>(K, u, v, lengths);
}